// Round 7
// baseline (879.772 us; speedup 1.0000x reference)
//
#include <hip/hip_runtime.h>
#include <math.h>

#define T_STEPS 120
#define BATCH   1024

typedef __attribute__((ext_vector_type(8))) short bf16x8;
typedef __attribute__((ext_vector_type(4))) float f32x4;
typedef __attribute__((ext_vector_type(4))) unsigned short us4;

// GEMM LDS slot swizzle (unchanged, proven)
__device__ __forceinline__ int gsw(int r) { return (r & 7) ^ ((r >> 3) & 1); }

// split f into hi (truncated bf16) + lo (RNE bf16 of remainder); f ~= hi+lo
// returns (hi << 16) | lo
__device__ __forceinline__ unsigned split2(float f) {
    union { float f; unsigned u; } a; a.f = f;
    unsigned hi = a.u >> 16;
    union { float f; unsigned u; } h; h.u = a.u & 0xFFFF0000u;
    union { float f; unsigned u; } b; b.f = f - h.f;
    unsigned rr = b.u + 0x7FFFu + ((b.u >> 16) & 1);
    return (hi << 16) | (rr >> 16);
}

__device__ __forceinline__ float fast_sigmoid(float x) {
    float e = __expf(-x);
    return __builtin_amdgcn_rcpf(1.f + e);
}

// barrier that does NOT drain vmcnt: LDS-visibility only. Keeps xz prefetch
// loads and h global stores in flight across the step boundary.
__device__ __forceinline__ void block_sync_lds() {
    asm volatile("s_waitcnt lgkmcnt(0)" ::: "memory");
    __builtin_amdgcn_sched_barrier(0);
    __builtin_amdgcn_s_barrier();
    __builtin_amdgcn_sched_barrier(0);
}

// ---------------------------------------------------------------------------
// Split-bf16 MFMA GEMM. C written in rec-friendly layout:
//   C4[bg][t][z][4] where bg = batch/4, inner index = batch%4.
// ---------------------------------------------------------------------------
__global__ __launch_bounds__(256, 2)
void gemm_xz_mfma(const float* __restrict__ A,   // (B, T, K)
                  const float* __restrict__ Bw,  // (K, N)
                  float* __restrict__ C,         // (B/4, TC, N, 4)
                  int N, int K, int TC, int t0)
{
    constexpr int BM = 128, BN = 64, BK = 64;
    __shared__ unsigned short Ah[BM * BK], Al[BM * BK];
    __shared__ unsigned short Bh[BN * BK], Bl[BN * BK];

    const int tid  = threadIdx.x;
    const int lane = tid & 63;
    const int wv   = tid >> 6;
    const int wm   = wv & 1;
    const int wn   = wv >> 1;
    const int m0   = blockIdx.x * BM;
    const int n0   = blockIdx.y * BN;

    f32x4 acc[4][2] = {};

    const int ktiles = (K + BK - 1) / BK;
    for (int kt = 0; kt < ktiles; ++kt) {
        const int kb = kt * BK;
        __syncthreads();

        {
            const int f4   = tid & 15;
            const int sub  = (f4 & 1) * 4;
            const int k8   = f4 >> 1;
            const int kidx = kb + f4 * 4;
            const bool kok = (kidx < K);
            for (int rd = 0; rd < 8; ++rd) {
                int m  = rd * 16 + (tid >> 4);
                int gm = m0 + m;
                int b  = gm / TC;
                int tt = t0 + (gm - b * TC);
                float4 v = make_float4(0.f, 0.f, 0.f, 0.f);
                if (kok)
                    v = *reinterpret_cast<const float4*>(
                            &A[((size_t)b * T_STEPS + tt) * K + kidx]);
                unsigned px = split2(v.x), py = split2(v.y);
                unsigned pz = split2(v.z), pw = split2(v.w);
                us4 hh, ll;
                hh.x = (unsigned short)(px >> 16); ll.x = (unsigned short)px;
                hh.y = (unsigned short)(py >> 16); ll.y = (unsigned short)py;
                hh.z = (unsigned short)(pz >> 16); ll.z = (unsigned short)pz;
                hh.w = (unsigned short)(pw >> 16); ll.w = (unsigned short)pw;
                int off = m * 64 + ((k8 ^ gsw(m & 15)) * 8) + sub;
                *reinterpret_cast<us4*>(&Ah[off]) = hh;
                *reinterpret_cast<us4*>(&Al[off]) = ll;
            }
        }
        {
#pragma unroll
            for (int i = 0; i < 2; ++i) {
                int u  = tid + i * 256;
                int n  = u & 63;
                int k8 = u >> 6;
                unsigned short th[8], tl[8];
#pragma unroll
                for (int e = 0; e < 8; ++e) {
                    int k = kb + k8 * 8 + e;
                    float f = (k < K) ? Bw[(size_t)k * N + n0 + n] : 0.f;
                    unsigned p = split2(f);
                    th[e] = (unsigned short)(p >> 16);
                    tl[e] = (unsigned short)p;
                }
                us4 h0, h1, l0, l1;
                h0.x = th[0]; h0.y = th[1]; h0.z = th[2]; h0.w = th[3];
                h1.x = th[4]; h1.y = th[5]; h1.z = th[6]; h1.w = th[7];
                l0.x = tl[0]; l0.y = tl[1]; l0.z = tl[2]; l0.w = tl[3];
                l1.x = tl[4]; l1.y = tl[5]; l1.z = tl[6]; l1.w = tl[7];
                int off = n * 64 + ((k8 ^ gsw(n & 15)) * 8);
                *reinterpret_cast<us4*>(&Bh[off])     = h0;
                *reinterpret_cast<us4*>(&Bh[off + 4]) = h1;
                *reinterpret_cast<us4*>(&Bl[off])     = l0;
                *reinterpret_cast<us4*>(&Bl[off + 4]) = l1;
            }
        }
        __syncthreads();

        const int row = lane & 15;
        const int kq  = lane >> 4;
        const int gr  = gsw(row);
#pragma unroll
        for (int ks = 0; ks < 2; ++ks) {
            const int k8 = ks * 4 + kq;
            bf16x8 bh[2], bl[2];
#pragma unroll
            for (int ni = 0; ni < 2; ++ni) {
                int n = wn * 32 + ni * 16 + row;
                int off = n * 64 + ((k8 ^ gr) * 8);
                bh[ni] = *reinterpret_cast<const bf16x8*>(&Bh[off]);
                bl[ni] = *reinterpret_cast<const bf16x8*>(&Bl[off]);
            }
#pragma unroll
            for (int mi = 0; mi < 4; ++mi) {
                int m = wm * 64 + mi * 16 + row;
                int off = m * 64 + ((k8 ^ gr) * 8);
                bf16x8 ah = *reinterpret_cast<const bf16x8*>(&Ah[off]);
                bf16x8 al = *reinterpret_cast<const bf16x8*>(&Al[off]);
#pragma unroll
                for (int ni = 0; ni < 2; ++ni) {
                    acc[mi][ni] = __builtin_amdgcn_mfma_f32_16x16x32_bf16(ah, bh[ni], acc[mi][ni], 0, 0, 0);
                    acc[mi][ni] = __builtin_amdgcn_mfma_f32_16x16x32_bf16(ah, bl[ni], acc[mi][ni], 0, 0, 0);
                    acc[mi][ni] = __builtin_amdgcn_mfma_f32_16x16x32_bf16(al, bh[ni], acc[mi][ni], 0, 0, 0);
                }
            }
        }
    }

    // epilogue: C/D layout col = lane&15, row = (lane>>4)*4 + reg
    const int col = lane & 15;
    const int rq  = (lane >> 4) * 4;
#pragma unroll
    for (int mi = 0; mi < 4; ++mi) {
#pragma unroll
        for (int r = 0; r < 4; ++r) {
            int gm = m0 + wm * 64 + mi * 16 + rq + r;
            int b  = gm / TC;
            int tl = gm - b * TC;
#pragma unroll
            for (int ni = 0; ni < 2; ++ni) {
                int n = n0 + wn * 32 + ni * 16 + col;
                C[(((size_t)(b >> 2) * TC + tl) * N + n) * 4 + (b & 3)] = acc[mi][ni][r];
            }
        }
    }
}

// ---------------------------------------------------------------------------
// MFMA recurrent scan. Block = 16 batch rows, grid = 64, NW waves.
// Wave wid owns z-cols { p*U + wid*16 + ln }. Weights register-resident
// (forced by amdgpu_waves_per_eu(2,2): 256-VGPR budget, no spill).
// h in LDS as packed (hi|lo) u32, 16B-granular XOR swizzle, double-buffered.
// Raw lgkm-only barrier per step: xz prefetch + h stores fly across it.
// xz read as float4 from [bg][t][z][4] layout.
// ---------------------------------------------------------------------------
template<int U, int NW>
__global__ __launch_bounds__(NW * 64)
__attribute__((amdgpu_waves_per_eu(2, 2)))
void lstm_rec_mfma(const float* __restrict__ xz,    // (B/4, TC, 4U, 4)
                   const float* __restrict__ Uw,    // (U, 4U)
                   const float* __restrict__ bias,  // (4U)
                   float* __restrict__ hout,        // (B,T,U) or (B,U)
                   float* __restrict__ cst,         // (B,U)
                   float* __restrict__ hst,         // (B,U)
                   int TC, int t0, int last_only)
{
    constexpr int NZ = 4 * U;
    constexpr int KT = U / 32;
    constexpr int NB = 16;
    static_assert(NW * 16 == U, "waves cover all units");

    __shared__ unsigned hsh[2][NB][U];

#define SWZ(b, c) ((c) ^ (((b) & 7) << 2))

    const int tid  = threadIdx.x;
    const int lane = tid & 63;
    const int wid  = tid >> 6;
    const int ln   = lane & 15;
    const int lq   = lane >> 4;
    const int b0   = blockIdx.x * NB;
    const int unit = wid * 16 + ln;
    const int bg   = blockIdx.x * 4 + lq;      // batch group of 4

    // ---- weights into registers, pre-split ----
    bf16x8 bwh[4][KT], bwl[4][KT];
#pragma unroll
    for (int p = 0; p < 4; ++p)
#pragma unroll
        for (int kt = 0; kt < KT; ++kt) {
#pragma unroll
            for (int e = 0; e < 8; ++e) {
                int k = kt * 32 + lq * 8 + e;
                unsigned s = split2(Uw[(size_t)k * NZ + p * U + unit]);
                bwh[p][kt][e] = (short)(s >> 16);
                bwl[p][kt][e] = (short)(s & 0xFFFFu);
            }
        }
    float breg[4];
#pragma unroll
    for (int p = 0; p < 4; ++p) breg[p] = bias[p * U + unit];

    // ---- state init ----
    float creg[4], hlast[4];
#pragma unroll
    for (int r = 0; r < 4; ++r) {
        int br = lq * 4 + r;
        float c0 = 0.f, h0 = 0.f;
        if (t0 != 0) {
            c0 = cst[(size_t)(b0 + br) * U + unit];
            h0 = hst[(size_t)(b0 + br) * U + unit];
        }
        creg[r] = c0; hlast[r] = h0;
        hsh[0][br][SWZ(br, unit)] = split2(h0);
    }

    // prefetch xz for t=0: one float4 per p (4 batches of this lane's group)
    f32x4 xzv[4];
#pragma unroll
    for (int p = 0; p < 4; ++p)
        xzv[p] = *reinterpret_cast<const f32x4*>(
            &xz[(((size_t)bg * TC + 0) * NZ + p * U + unit) * 4]);

    block_sync_lds();

    int cur = 0;
    for (int t = 0; t < TC; ++t) {
        // ---- A-frags from LDS (swizzled, 2-way-free banks) ----
        bf16x8 ah[KT], al[KT];
#pragma unroll
        for (int kt = 0; kt < KT; ++kt) {
            const unsigned* pa = &hsh[cur][ln][0];
            int base = kt * 32 + lq * 8;
            uint4 u0 = *reinterpret_cast<const uint4*>(pa + SWZ(ln, base));
            uint4 u1 = *reinterpret_cast<const uint4*>(pa + SWZ(ln, base + 4));
            unsigned uu[8] = {u0.x, u0.y, u0.z, u0.w, u1.x, u1.y, u1.z, u1.w};
#pragma unroll
            for (int e = 0; e < 8; ++e) {
                ah[kt][e] = (short)(uu[e] >> 16);
                al[kt][e] = (short)(uu[e] & 0xFFFFu);
            }
        }

        // ---- acc init = xz + bias ----
        f32x4 acc[4];
#pragma unroll
        for (int p = 0; p < 4; ++p)
#pragma unroll
            for (int r = 0; r < 4; ++r)
                acc[p][r] = xzv[p][r] + breg[p];

        // prefetch next xz (stays in flight across the raw barrier)
        if (t + 1 < TC) {
#pragma unroll
            for (int p = 0; p < 4; ++p)
                xzv[p] = *reinterpret_cast<const f32x4*>(
                    &xz[(((size_t)bg * TC + (t + 1)) * NZ + p * U + unit) * 4]);
        }

        // ---- z += h @ U (3-term split-bf16) ----
#pragma unroll
        for (int kt = 0; kt < KT; ++kt)
#pragma unroll
            for (int p = 0; p < 4; ++p) {
                acc[p] = __builtin_amdgcn_mfma_f32_16x16x32_bf16(ah[kt], bwh[p][kt], acc[p], 0, 0, 0);
                acc[p] = __builtin_amdgcn_mfma_f32_16x16x32_bf16(ah[kt], bwl[p][kt], acc[p], 0, 0, 0);
                acc[p] = __builtin_amdgcn_mfma_f32_16x16x32_bf16(al[kt], bwh[p][kt], acc[p], 0, 0, 0);
            }

        // ---- gates, state, h ----
#pragma unroll
        for (int r = 0; r < 4; ++r) {
            float si = fast_sigmoid(acc[0][r]);
            float sf = fast_sigmoid(acc[1][r]);
            float g  = fmaxf(acc[2][r], 0.f);
            float so = fast_sigmoid(acc[3][r]);
            float c  = sf * creg[r] + si * g;
            creg[r] = c;
            float h = so * fmaxf(c, 0.f);
            hlast[r] = h;
            int br = lq * 4 + r;
            hsh[cur ^ 1][br][SWZ(br, unit)] = split2(h);
            if (!last_only)
                hout[((size_t)(b0 + br) * T_STEPS + (t0 + t)) * U + unit] = h;
            else if (t0 + t == T_STEPS - 1)
                hout[(size_t)(b0 + br) * U + unit] = h;
        }
        block_sync_lds();
        cur ^= 1;
    }

#pragma unroll
    for (int r = 0; r < 4; ++r) {
        int br = lq * 4 + r;
        cst[(size_t)(b0 + br) * U + unit] = creg[r];
        hst[(size_t)(b0 + br) * U + unit] = hlast[r];
    }
#undef SWZ
}

// Dense head: one wave per batch row. 64 ->relu-> 64 ->relu-> 32 -> 101 -> softmax
__global__ __launch_bounds__(256)
void dense_head(const float* __restrict__ h3,    // (B,64)
                const float* __restrict__ Wd1, const float* __restrict__ bd1,
                const float* __restrict__ Wd2, const float* __restrict__ bd2,
                const float* __restrict__ Wd3, const float* __restrict__ bd3,
                float* __restrict__ out)         // (B,101)
{
    __shared__ float s1[4][64];
    __shared__ float s2[4][32];
    const int w    = threadIdx.x >> 6;
    const int lane = threadIdx.x & 63;
    const int row  = blockIdx.x * 4 + w;

    float hval = h3[(size_t)row * 64 + lane];
    float a = bd1[lane];
#pragma unroll
    for (int k = 0; k < 64; ++k) {
        float hk = __shfl(hval, k, 64);
        a = fmaf(hk, Wd1[k * 64 + lane], a);
    }
    s1[w][lane] = fmaxf(a, 0.f);
    __syncthreads();

    if (lane < 32) {
        float a2 = bd2[lane];
#pragma unroll
        for (int k = 0; k < 64; ++k) a2 = fmaf(s1[w][k], Wd2[k * 32 + lane], a2);
        s2[w][lane] = fmaxf(a2, 0.f);
    }
    __syncthreads();

    float a0 = bd3[lane];
#pragma unroll
    for (int k = 0; k < 32; ++k) a0 = fmaf(s2[w][k], Wd3[k * 101 + lane], a0);
    float a1 = -INFINITY;
    if (lane < 37) {
        a1 = bd3[64 + lane];
#pragma unroll
        for (int k = 0; k < 32; ++k) a1 = fmaf(s2[w][k], Wd3[k * 101 + 64 + lane], a1);
    }

    float m = fmaxf(a0, a1);
#pragma unroll
    for (int off = 32; off > 0; off >>= 1) m = fmaxf(m, __shfl_xor(m, off, 64));
    float e0 = expf(a0 - m);
    float e1 = (lane < 37) ? expf(a1 - m) : 0.f;
    float s = e0 + e1;
#pragma unroll
    for (int off = 32; off > 0; off >>= 1) s += __shfl_xor(s, off, 64);

    out[(size_t)row * 101 + lane] = e0 / s;
    if (lane < 37) out[(size_t)row * 101 + 64 + lane] = e1 / s;
}

extern "C" void kernel_launch(void* const* d_in, const int* in_sizes, int n_in,
                              void* d_out, int out_size, void* d_ws, size_t ws_size,
                              hipStream_t stream) {
    const float* x   = (const float*)d_in[0];
    const float* W1  = (const float*)d_in[1];
    const float* U1  = (const float*)d_in[2];
    const float* b1  = (const float*)d_in[3];
    const float* W2  = (const float*)d_in[4];
    const float* U2  = (const float*)d_in[5];
    const float* b2  = (const float*)d_in[6];
    const float* W3  = (const float*)d_in[7];
    const float* U3  = (const float*)d_in[8];
    const float* b3  = (const float*)d_in[9];
    const float* Wd1 = (const float*)d_in[10];
    const float* bd1 = (const float*)d_in[11];
    const float* Wd2 = (const float*)d_in[12];
    const float* bd2 = (const float*)d_in[13];
    const float* Wd3 = (const float*)d_in[14];
    const float* bd3 = (const float*)d_in[15];

    // workspace layout (floats); peak ~160 MB
    float* xzbuf = (float*)d_ws;                      // up to 1024*60*256
    float* h1  = xzbuf + 15728640;                    // 1024*120*64
    float* h2  = h1 + 7864320;                        // 1024*120*128
    float* h3  = h2 + 15728640;                       // 1024*64
    float* c1  = h3 + 65536;
    float* hs1 = c1 + 65536;
    float* c2  = hs1 + 65536;                         // 1024*128
    float* hs2 = c2 + 131072;
    float* c3  = hs2 + 131072;
    float* hs3 = c3 + 65536;

    // Layer 1: K=132 -> 4U=256, time chunks of 60
    for (int ch = 0; ch < 2; ++ch) {
        gemm_xz_mfma<<<dim3(480, 4), 256, 0, stream>>>(x, W1, xzbuf, 256, 132, 60, ch * 60);
        lstm_rec_mfma<64, 4><<<64, 256, 0, stream>>>(xzbuf, U1, b1, h1, c1, hs1, 60, ch * 60, 0);
    }
    // Layer 2: K=64 -> 4U=512, time chunks of 30
    for (int ch = 0; ch < 4; ++ch) {
        gemm_xz_mfma<<<dim3(240, 8), 256, 0, stream>>>(h1, W2, xzbuf, 512, 64, 30, ch * 30);
        lstm_rec_mfma<128, 8><<<64, 512, 0, stream>>>(xzbuf, U2, b2, h2, c2, hs2, 30, ch * 30, 0);
    }
    // Layer 3: K=128 -> 4U=256, time chunks of 60, last hidden only
    for (int ch = 0; ch < 2; ++ch) {
        gemm_xz_mfma<<<dim3(480, 4), 256, 0, stream>>>(h2, W3, xzbuf, 256, 128, 60, ch * 60);
        lstm_rec_mfma<64, 4><<<64, 256, 0, stream>>>(xzbuf, U3, b3, h3, c3, hs3, 60, ch * 60, 1);
    }
    dense_head<<<256, 256, 0, stream>>>(h3, Wd1, bd1, Wd2, bd2, Wd3, bd3, (float*)d_out);
}

// Round 8
// 808.805 us; speedup vs baseline: 1.0877x; 1.0877x over previous
//
#include <hip/hip_runtime.h>
#include <math.h>

#define T_STEPS 120
#define BATCH   1024

typedef __attribute__((ext_vector_type(8))) short bf16x8;
typedef __attribute__((ext_vector_type(4))) float f32x4;
typedef __attribute__((ext_vector_type(4))) unsigned short us4;

// GEMM LDS slot swizzle (proven)
__device__ __forceinline__ int gsw(int r) { return (r & 7) ^ ((r >> 3) & 1); }

// split f into hi (truncated bf16) + lo (RNE bf16 of remainder); f ~= hi+lo
// returns (hi << 16) | lo
__device__ __forceinline__ unsigned split2(float f) {
    union { float f; unsigned u; } a; a.f = f;
    unsigned hi = a.u >> 16;
    union { float f; unsigned u; } h; h.u = a.u & 0xFFFF0000u;
    union { float f; unsigned u; } b; b.f = f - h.f;
    unsigned rr = b.u + 0x7FFFu + ((b.u >> 16) & 1);
    return (hi << 16) | (rr >> 16);
}

__device__ __forceinline__ float fast_sigmoid(float x) {
    float e = __expf(-x);
    return __builtin_amdgcn_rcpf(1.f + e);
}

// barrier that does NOT drain vmcnt: LDS-visibility only. Keeps xz prefetch
// loads and h global stores in flight across the step boundary.
__device__ __forceinline__ void block_sync_lds() {
    asm volatile("s_waitcnt lgkmcnt(0)" ::: "memory");
    __builtin_amdgcn_sched_barrier(0);
    __builtin_amdgcn_s_barrier();
    __builtin_amdgcn_sched_barrier(0);
}

// ---------------------------------------------------------------------------
// Split-bf16 MFMA GEMM: C[m,n] = sum_k A'[m,k]*Bw[k,n], compact C (B,TC,N).
// Coalesced C writes (n contiguous across lanes).
// ---------------------------------------------------------------------------
__global__ __launch_bounds__(256, 2)
void gemm_xz_mfma(const float* __restrict__ A,   // (B, T, K)
                  const float* __restrict__ Bw,  // (K, N)
                  float* __restrict__ C,         // (B, TC, N)
                  int N, int K, int TC, int t0)
{
    constexpr int BM = 128, BN = 64, BK = 64;
    __shared__ unsigned short Ah[BM * BK], Al[BM * BK];
    __shared__ unsigned short Bh[BN * BK], Bl[BN * BK];

    const int tid  = threadIdx.x;
    const int lane = tid & 63;
    const int wv   = tid >> 6;
    const int wm   = wv & 1;
    const int wn   = wv >> 1;
    const int m0   = blockIdx.x * BM;
    const int n0   = blockIdx.y * BN;

    f32x4 acc[4][2] = {};

    const int ktiles = (K + BK - 1) / BK;
    for (int kt = 0; kt < ktiles; ++kt) {
        const int kb = kt * BK;
        __syncthreads();

        {
            const int f4   = tid & 15;
            const int sub  = (f4 & 1) * 4;
            const int k8   = f4 >> 1;
            const int kidx = kb + f4 * 4;
            const bool kok = (kidx < K);
            for (int rd = 0; rd < 8; ++rd) {
                int m  = rd * 16 + (tid >> 4);
                int gm = m0 + m;
                int b  = gm / TC;
                int tt = t0 + (gm - b * TC);
                float4 v = make_float4(0.f, 0.f, 0.f, 0.f);
                if (kok)
                    v = *reinterpret_cast<const float4*>(
                            &A[((size_t)b * T_STEPS + tt) * K + kidx]);
                unsigned px = split2(v.x), py = split2(v.y);
                unsigned pz = split2(v.z), pw = split2(v.w);
                us4 hh, ll;
                hh.x = (unsigned short)(px >> 16); ll.x = (unsigned short)px;
                hh.y = (unsigned short)(py >> 16); ll.y = (unsigned short)py;
                hh.z = (unsigned short)(pz >> 16); ll.z = (unsigned short)pz;
                hh.w = (unsigned short)(pw >> 16); ll.w = (unsigned short)pw;
                int off = m * 64 + ((k8 ^ gsw(m & 15)) * 8) + sub;
                *reinterpret_cast<us4*>(&Ah[off]) = hh;
                *reinterpret_cast<us4*>(&Al[off]) = ll;
            }
        }
        {
#pragma unroll
            for (int i = 0; i < 2; ++i) {
                int u  = tid + i * 256;
                int n  = u & 63;
                int k8 = u >> 6;
                unsigned short th[8], tl[8];
#pragma unroll
                for (int e = 0; e < 8; ++e) {
                    int k = kb + k8 * 8 + e;
                    float f = (k < K) ? Bw[(size_t)k * N + n0 + n] : 0.f;
                    unsigned p = split2(f);
                    th[e] = (unsigned short)(p >> 16);
                    tl[e] = (unsigned short)p;
                }
                us4 h0, h1, l0, l1;
                h0.x = th[0]; h0.y = th[1]; h0.z = th[2]; h0.w = th[3];
                h1.x = th[4]; h1.y = th[5]; h1.z = th[6]; h1.w = th[7];
                l0.x = tl[0]; l0.y = tl[1]; l0.z = tl[2]; l0.w = tl[3];
                l1.x = tl[4]; l1.y = tl[5]; l1.z = tl[6]; l1.w = tl[7];
                int off = n * 64 + ((k8 ^ gsw(n & 15)) * 8);
                *reinterpret_cast<us4*>(&Bh[off])     = h0;
                *reinterpret_cast<us4*>(&Bh[off + 4]) = h1;
                *reinterpret_cast<us4*>(&Bl[off])     = l0;
                *reinterpret_cast<us4*>(&Bl[off + 4]) = l1;
            }
        }
        __syncthreads();

        const int row = lane & 15;
        const int kq  = lane >> 4;
        const int gr  = gsw(row);
#pragma unroll
        for (int ks = 0; ks < 2; ++ks) {
            const int k8 = ks * 4 + kq;
            bf16x8 bh[2], bl[2];
#pragma unroll
            for (int ni = 0; ni < 2; ++ni) {
                int n = wn * 32 + ni * 16 + row;
                int off = n * 64 + ((k8 ^ gr) * 8);
                bh[ni] = *reinterpret_cast<const bf16x8*>(&Bh[off]);
                bl[ni] = *reinterpret_cast<const bf16x8*>(&Bl[off]);
            }
#pragma unroll
            for (int mi = 0; mi < 4; ++mi) {
                int m = wm * 64 + mi * 16 + row;
                int off = m * 64 + ((k8 ^ gr) * 8);
                bf16x8 ah = *reinterpret_cast<const bf16x8*>(&Ah[off]);
                bf16x8 al = *reinterpret_cast<const bf16x8*>(&Al[off]);
#pragma unroll
                for (int ni = 0; ni < 2; ++ni) {
                    acc[mi][ni] = __builtin_amdgcn_mfma_f32_16x16x32_bf16(ah, bh[ni], acc[mi][ni], 0, 0, 0);
                    acc[mi][ni] = __builtin_amdgcn_mfma_f32_16x16x32_bf16(ah, bl[ni], acc[mi][ni], 0, 0, 0);
                    acc[mi][ni] = __builtin_amdgcn_mfma_f32_16x16x32_bf16(al, bh[ni], acc[mi][ni], 0, 0, 0);
                }
            }
        }
    }

    // epilogue: C/D layout col = lane&15, row = (lane>>4)*4 + reg.
    // n contiguous across lanes -> coalesced 64B runs.
    const int col = lane & 15;
    const int rq  = (lane >> 4) * 4;
#pragma unroll
    for (int mi = 0; mi < 4; ++mi) {
#pragma unroll
        for (int r = 0; r < 4; ++r) {
            int gm = m0 + wm * 64 + mi * 16 + rq + r;
            int b  = gm / TC;
            int tl = gm - b * TC;
#pragma unroll
            for (int ni = 0; ni < 2; ++ni) {
                int n = n0 + wn * 32 + ni * 16 + col;
                C[((size_t)b * TC + tl) * N + n] = acc[mi][ni][r];
            }
        }
    }
}

// ---------------------------------------------------------------------------
// MFMA recurrent scan. Block = 16 batch rows, grid = 64, NW waves.
// Wave wid owns z-cols { p*U + wid*16 + ln }. Weights register-resident
// (amdgpu_waves_per_eu(2,2): 256-VGPR budget, no spill).
// h in LDS as packed (hi|lo) u32, 16B-granular XOR swizzle, double-buffered.
// Raw lgkm-only barrier per step: xz prefetch + h stores fly across it.
// ---------------------------------------------------------------------------
template<int U, int NW>
__global__ __launch_bounds__(NW * 64)
__attribute__((amdgpu_waves_per_eu(2, 2)))
void lstm_rec_mfma(const float* __restrict__ xz,    // (B, TC, 4U) chunk
                   const float* __restrict__ Uw,    // (U, 4U)
                   const float* __restrict__ bias,  // (4U)
                   float* __restrict__ hout,        // (B,T,U) or (B,U)
                   float* __restrict__ cst,         // (B,U)
                   float* __restrict__ hst,         // (B,U)
                   int TC, int t0, int last_only)
{
    constexpr int NZ = 4 * U;
    constexpr int KT = U / 32;
    constexpr int NB = 16;
    static_assert(NW * 16 == U, "waves cover all units");

    __shared__ unsigned hsh[2][NB][U];

#define SWZ(b, c) ((c) ^ (((b) & 7) << 2))

    const int tid  = threadIdx.x;
    const int lane = tid & 63;
    const int wid  = tid >> 6;
    const int ln   = lane & 15;
    const int lq   = lane >> 4;
    const int b0   = blockIdx.x * NB;
    const int unit = wid * 16 + ln;

    // ---- weights into registers, pre-split ----
    bf16x8 bwh[4][KT], bwl[4][KT];
#pragma unroll
    for (int p = 0; p < 4; ++p)
#pragma unroll
        for (int kt = 0; kt < KT; ++kt) {
#pragma unroll
            for (int e = 0; e < 8; ++e) {
                int k = kt * 32 + lq * 8 + e;
                unsigned s = split2(Uw[(size_t)k * NZ + p * U + unit]);
                bwh[p][kt][e] = (short)(s >> 16);
                bwl[p][kt][e] = (short)(s & 0xFFFFu);
            }
        }
    float breg[4];
#pragma unroll
    for (int p = 0; p < 4; ++p) breg[p] = bias[p * U + unit];

    // ---- state init ----
    float creg[4], hlast[4];
#pragma unroll
    for (int r = 0; r < 4; ++r) {
        int br = lq * 4 + r;
        float c0 = 0.f, h0 = 0.f;
        if (t0 != 0) {
            c0 = cst[(size_t)(b0 + br) * U + unit];
            h0 = hst[(size_t)(b0 + br) * U + unit];
        }
        creg[r] = c0; hlast[r] = h0;
        hsh[0][br][SWZ(br, unit)] = split2(h0);
    }

    // prefetch xz for t=0 (scalar; coalesces in 64B runs across each 16-lane group)
    float xzv[4][4];    // [p][r]
#pragma unroll
    for (int p = 0; p < 4; ++p)
#pragma unroll
        for (int r = 0; r < 4; ++r)
            xzv[p][r] = xz[((size_t)(b0 + lq * 4 + r) * TC + 0) * NZ + p * U + unit];

    block_sync_lds();

    int cur = 0;
    for (int t = 0; t < TC; ++t) {
        // ---- A-frags from LDS (swizzled, 2-way-free banks) ----
        bf16x8 ah[KT], al[KT];
#pragma unroll
        for (int kt = 0; kt < KT; ++kt) {
            const unsigned* pa = &hsh[cur][ln][0];
            int base = kt * 32 + lq * 8;
            uint4 u0 = *reinterpret_cast<const uint4*>(pa + SWZ(ln, base));
            uint4 u1 = *reinterpret_cast<const uint4*>(pa + SWZ(ln, base + 4));
            unsigned uu[8] = {u0.x, u0.y, u0.z, u0.w, u1.x, u1.y, u1.z, u1.w};
#pragma unroll
            for (int e = 0; e < 8; ++e) {
                ah[kt][e] = (short)(uu[e] >> 16);
                al[kt][e] = (short)(uu[e] & 0xFFFFu);
            }
        }

        // ---- acc init = xz + bias ----
        f32x4 acc[4];
#pragma unroll
        for (int p = 0; p < 4; ++p)
#pragma unroll
            for (int r = 0; r < 4; ++r)
                acc[p][r] = xzv[p][r] + breg[p];

        // prefetch next xz (stays in flight across the raw barrier)
        if (t + 1 < TC) {
#pragma unroll
            for (int p = 0; p < 4; ++p)
#pragma unroll
                for (int r = 0; r < 4; ++r)
                    xzv[p][r] = xz[((size_t)(b0 + lq * 4 + r) * TC + (t + 1)) * NZ + p * U + unit];
        }

        // ---- z += h @ U (3-term split-bf16) ----
#pragma unroll
        for (int kt = 0; kt < KT; ++kt)
#pragma unroll
            for (int p = 0; p < 4; ++p) {
                acc[p] = __builtin_amdgcn_mfma_f32_16x16x32_bf16(ah[kt], bwh[p][kt], acc[p], 0, 0, 0);
                acc[p] = __builtin_amdgcn_mfma_f32_16x16x32_bf16(ah[kt], bwl[p][kt], acc[p], 0, 0, 0);
                acc[p] = __builtin_amdgcn_mfma_f32_16x16x32_bf16(al[kt], bwh[p][kt], acc[p], 0, 0, 0);
            }

        // ---- gates, state, h ----
#pragma unroll
        for (int r = 0; r < 4; ++r) {
            float si = fast_sigmoid(acc[0][r]);
            float sf = fast_sigmoid(acc[1][r]);
            float g  = fmaxf(acc[2][r], 0.f);
            float so = fast_sigmoid(acc[3][r]);
            float c  = sf * creg[r] + si * g;
            creg[r] = c;
            float h = so * fmaxf(c, 0.f);
            hlast[r] = h;
            int br = lq * 4 + r;
            hsh[cur ^ 1][br][SWZ(br, unit)] = split2(h);
            if (!last_only)
                hout[((size_t)(b0 + br) * T_STEPS + (t0 + t)) * U + unit] = h;
            else if (t0 + t == T_STEPS - 1)
                hout[(size_t)(b0 + br) * U + unit] = h;
        }
        block_sync_lds();
        cur ^= 1;
    }

#pragma unroll
    for (int r = 0; r < 4; ++r) {
        int br = lq * 4 + r;
        cst[(size_t)(b0 + br) * U + unit] = creg[r];
        hst[(size_t)(b0 + br) * U + unit] = hlast[r];
    }
#undef SWZ
}

// Dense head: one wave per batch row. 64 ->relu-> 64 ->relu-> 32 -> 101 -> softmax
__global__ __launch_bounds__(256)
void dense_head(const float* __restrict__ h3,    // (B,64)
                const float* __restrict__ Wd1, const float* __restrict__ bd1,
                const float* __restrict__ Wd2, const float* __restrict__ bd2,
                const float* __restrict__ Wd3, const float* __restrict__ bd3,
                float* __restrict__ out)         // (B,101)
{
    __shared__ float s1[4][64];
    __shared__ float s2[4][32];
    const int w    = threadIdx.x >> 6;
    const int lane = threadIdx.x & 63;
    const int row  = blockIdx.x * 4 + w;

    float hval = h3[(size_t)row * 64 + lane];
    float a = bd1[lane];
#pragma unroll
    for (int k = 0; k < 64; ++k) {
        float hk = __shfl(hval, k, 64);
        a = fmaf(hk, Wd1[k * 64 + lane], a);
    }
    s1[w][lane] = fmaxf(a, 0.f);
    __syncthreads();

    if (lane < 32) {
        float a2 = bd2[lane];
#pragma unroll
        for (int k = 0; k < 64; ++k) a2 = fmaf(s1[w][k], Wd2[k * 32 + lane], a2);
        s2[w][lane] = fmaxf(a2, 0.f);
    }
    __syncthreads();

    float a0 = bd3[lane];
#pragma unroll
    for (int k = 0; k < 32; ++k) a0 = fmaf(s2[w][k], Wd3[k * 101 + lane], a0);
    float a1 = -INFINITY;
    if (lane < 37) {
        a1 = bd3[64 + lane];
#pragma unroll
        for (int k = 0; k < 32; ++k) a1 = fmaf(s2[w][k], Wd3[k * 101 + 64 + lane], a1);
    }

    float m = fmaxf(a0, a1);
#pragma unroll
    for (int off = 32; off > 0; off >>= 1) m = fmaxf(m, __shfl_xor(m, off, 64));
    float e0 = expf(a0 - m);
    float e1 = (lane < 37) ? expf(a1 - m) : 0.f;
    float s = e0 + e1;
#pragma unroll
    for (int off = 32; off > 0; off >>= 1) s += __shfl_xor(s, off, 64);

    out[(size_t)row * 101 + lane] = e0 / s;
    if (lane < 37) out[(size_t)row * 101 + 64 + lane] = e1 / s;
}

extern "C" void kernel_launch(void* const* d_in, const int* in_sizes, int n_in,
                              void* d_out, int out_size, void* d_ws, size_t ws_size,
                              hipStream_t stream) {
    const float* x   = (const float*)d_in[0];
    const float* W1  = (const float*)d_in[1];
    const float* U1  = (const float*)d_in[2];
    const float* b1  = (const float*)d_in[3];
    const float* W2  = (const float*)d_in[4];
    const float* U2  = (const float*)d_in[5];
    const float* b2  = (const float*)d_in[6];
    const float* W3  = (const float*)d_in[7];
    const float* U3  = (const float*)d_in[8];
    const float* b3  = (const float*)d_in[9];
    const float* Wd1 = (const float*)d_in[10];
    const float* bd1 = (const float*)d_in[11];
    const float* Wd2 = (const float*)d_in[12];
    const float* bd2 = (const float*)d_in[13];
    const float* Wd3 = (const float*)d_in[14];
    const float* bd3 = (const float*)d_in[15];

    // workspace layout (floats); peak ~160 MB
    float* xzbuf = (float*)d_ws;                      // up to 1024*60*256
    float* h1  = xzbuf + 15728640;                    // 1024*120*64
    float* h2  = h1 + 7864320;                        // 1024*120*128
    float* h3  = h2 + 15728640;                       // 1024*64
    float* c1  = h3 + 65536;
    float* hs1 = c1 + 65536;
    float* c2  = hs1 + 65536;                         // 1024*128
    float* hs2 = c2 + 131072;
    float* c3  = hs2 + 131072;
    float* hs3 = c3 + 65536;

    // Layer 1: K=132 -> 4U=256, time chunks of 60
    for (int ch = 0; ch < 2; ++ch) {
        gemm_xz_mfma<<<dim3(480, 4), 256, 0, stream>>>(x, W1, xzbuf, 256, 132, 60, ch * 60);
        lstm_rec_mfma<64, 4><<<64, 256, 0, stream>>>(xzbuf, U1, b1, h1, c1, hs1, 60, ch * 60, 0);
    }
    // Layer 2: K=64 -> 4U=512, time chunks of 30
    for (int ch = 0; ch < 4; ++ch) {
        gemm_xz_mfma<<<dim3(240, 8), 256, 0, stream>>>(h1, W2, xzbuf, 512, 64, 30, ch * 30);
        lstm_rec_mfma<128, 8><<<64, 512, 0, stream>>>(xzbuf, U2, b2, h2, c2, hs2, 30, ch * 30, 0);
    }
    // Layer 3: K=128 -> 4U=256, time chunks of 60, last hidden only
    for (int ch = 0; ch < 2; ++ch) {
        gemm_xz_mfma<<<dim3(480, 4), 256, 0, stream>>>(h2, W3, xzbuf, 256, 128, 60, ch * 60);
        lstm_rec_mfma<64, 4><<<64, 256, 0, stream>>>(xzbuf, U3, b3, h3, c3, hs3, 60, ch * 60, 1);
    }
    dense_head<<<256, 256, 0, stream>>>(h3, Wd1, bd1, Wd2, bd2, Wd3, bd3, (float*)d_out);
}

// Round 9
// 806.737 us; speedup vs baseline: 1.0905x; 1.0026x over previous
//
#include <hip/hip_runtime.h>
#include <math.h>

#define T_STEPS 120
#define BATCH   1024

typedef __attribute__((ext_vector_type(8))) short bf16x8;
typedef __attribute__((ext_vector_type(4))) float f32x4;
typedef unsigned short u16;

// split f into hi (truncated bf16) + lo (RNE bf16 of remainder); f ~= hi+lo
// returns (hi << 16) | lo
__device__ __forceinline__ unsigned split2(float f) {
    union { float f; unsigned u; } a; a.f = f;
    unsigned hi = a.u >> 16;
    union { float f; unsigned u; } h; h.u = a.u & 0xFFFF0000u;
    union { float f; unsigned u; } b; b.f = f - h.f;
    unsigned rr = b.u + 0x7FFFu + ((b.u >> 16) & 1);
    return (hi << 16) | (rr >> 16);
}

__device__ __forceinline__ float fast_sigmoid(float x) {
    float e = __expf(-x);
    return __builtin_amdgcn_rcpf(1.f + e);
}

// LDS-visibility-only barrier: does NOT drain vmcnt, so global prefetch
// loads and h stores stay in flight across the step boundary.
__device__ __forceinline__ void block_sync_lds() {
    asm volatile("s_waitcnt lgkmcnt(0)" ::: "memory");
    __builtin_amdgcn_sched_barrier(0);
    __builtin_amdgcn_s_barrier();
    __builtin_amdgcn_sched_barrier(0);
}

// ---------------------------------------------------------------------------
// x (B,T,132) fp32 -> split bf16 hi/lo planes (B,T,144), zero-padded.
// Grid sized exactly: BATCH*T_STEPS*144 / 256 threads.
// ---------------------------------------------------------------------------
__global__ __launch_bounds__(256)
void xconv(const float* __restrict__ x, u16* __restrict__ xhi, u16* __restrict__ xlo)
{
    int idx = blockIdx.x * 256 + threadIdx.x;
    int k   = idx % 144;
    int bt  = idx / 144;
    float f = (k < 132) ? x[(size_t)bt * 132 + k] : 0.f;
    unsigned s = split2(f);
    xhi[idx] = (u16)(s >> 16);
    xlo[idx] = (u16)s;
}

// ---------------------------------------------------------------------------
// Fully fused LSTM layer: z_t = b + x_t @ W + h_{t-1} @ U, gates, scan.
// Block = 16 batch rows, grid = 64, NW waves (= U/16).
//  - W: LDS hi/lo planes, tiled [k8][n][8] (16-lane reads contiguous, 0-conflict)
//  - U: register-resident pre-split bf16 fragments
//  - x: global pre-split hi/lo planes, prefetched 1 step ahead (A-frag direct)
//  - h: LDS hi/lo planes, double-buffered; one lgkm-only barrier per step
//  - output: packed hi/lo h planes (next layer's x), or fp32 h_T if LAST_ONLY
// Logical K of x-part = 32*KTX; data width KXD may be smaller: in the last
// tile only lq < KTAIL lanes carry data, others use zero fragments.
// ---------------------------------------------------------------------------
template<int U, int KXD, int KTX, int KTAIL, int NW, bool LAST_ONLY>
__global__ __launch_bounds__(NW * 64)
__attribute__((amdgpu_waves_per_eu(2, 2)))
void lstm_fused(const u16* __restrict__ xhi, const u16* __restrict__ xlo,
                const float* __restrict__ W, int KIN,
                const float* __restrict__ Uw, const float* __restrict__ bias,
                u16* __restrict__ hhi, u16* __restrict__ hlo,
                float* __restrict__ hlast)
{
    constexpr int NZ  = 4 * U;
    constexpr int KTH = U / 32;
    constexpr int NB  = 16;
    constexpr int HPLANE = NB * U;              // u16 per h plane per buffer
    constexpr int WPLANE = (KXD / 8) * NZ * 8;  // u16 per W plane
    constexpr int LNZ = (NZ == 512) ? 9 : 8;

    __shared__ u16 lds[4 * HPLANE + 2 * WPLANE];
    u16* Whi = lds + 4 * HPLANE;
    u16* Wlo = Whi + WPLANE;

    const int tid  = threadIdx.x;
    const int lane = tid & 63;
    const int wid  = tid >> 6;
    const int ln   = lane & 15;
    const int lq   = lane >> 4;
    const int unit = wid * 16 + ln;
    const int b0   = blockIdx.x * NB;

    // ---- stage W into LDS planes (coalesced reads, one-time) ----
    for (int idx = tid; idx < KXD * NZ; idx += NW * 64) {
        int n = idx & (NZ - 1);
        int k = idx >> LNZ;
        float f = (k < KIN) ? W[(size_t)k * NZ + n] : 0.f;
        unsigned s = split2(f);
        int off = ((k >> 3) * NZ + n) * 8 + (k & 7);
        Whi[off] = (u16)(s >> 16);
        Wlo[off] = (u16)s;
    }

    // ---- U-weights into registers, pre-split ----
    bf16x8 bwh[4][KTH], bwl[4][KTH];
#pragma unroll
    for (int p = 0; p < 4; ++p)
#pragma unroll
        for (int kt = 0; kt < KTH; ++kt)
#pragma unroll
            for (int e = 0; e < 8; ++e) {
                int k = kt * 32 + lq * 8 + e;
                unsigned s = split2(Uw[(size_t)k * NZ + p * U + unit]);
                bwh[p][kt][e] = (short)(s >> 16);
                bwl[p][kt][e] = (short)(s & 0xFFFFu);
            }
    float breg[4];
#pragma unroll
    for (int p = 0; p < 4; ++p) breg[p] = bias[p * U + unit];

    // ---- h write pointers (per lane: 4 batch rows x 1 unit), zero buf0 ----
    u16* hw0 = lds + ((unit >> 3) * NB + lq * 4) * 8 + (unit & 7);
    u16* hw1 = hw0 + 2 * HPLANE;
    float creg[4];
#pragma unroll
    for (int r = 0; r < 4; ++r) {
        creg[r] = 0.f;
        hw0[r * 8] = 0;
        hw0[HPLANE + r * 8] = 0;
    }

    // ---- step-invariant read pointers ----
    const u16* hrd[2][KTH];
#pragma unroll
    for (int b = 0; b < 2; ++b)
#pragma unroll
        for (int kt = 0; kt < KTH; ++kt)
            hrd[b][kt] = lds + b * 2 * HPLANE + ((kt * 4 + lq) * NB + ln) * 8;

    const u16* wrh[KTX];
    const u16* wrl[KTX];
#pragma unroll
    for (int kt = 0; kt < KTX; ++kt) {
        int off = ((kt * 4 + lq) * NZ + wid * 16 + ln) * 8;
        wrh[kt] = Whi + off;
        wrl[kt] = Wlo + off;
    }

    // ---- x pointers + first prefetch (zero frags beyond data width) ----
    const u16* pxh = xhi + ((size_t)(b0 + ln) * T_STEPS) * KXD + lq * 8;
    const u16* pxl = xlo + ((size_t)(b0 + ln) * T_STEPS) * KXD + lq * 8;
    bf16x8 xph[KTX] = {};
    bf16x8 xpl[KTX] = {};
#pragma unroll
    for (int kt = 0; kt < KTX; ++kt)
        if (kt < KTX - 1 || lq < KTAIL) {
            xph[kt] = *reinterpret_cast<const bf16x8*>(pxh + kt * 32);
            xpl[kt] = *reinterpret_cast<const bf16x8*>(pxl + kt * 32);
        }

    // global h-plane output offset for r=0 (elements)
    size_t ho = ((size_t)(b0 + lq * 4) * T_STEPS) * U + unit;

    block_sync_lds();

#define STEP(CUR, OTH, tcur)                                                    \
    {                                                                           \
        bf16x8 ahh[KTH], ahl[KTH];                                              \
        _Pragma("unroll")                                                       \
        for (int kt = 0; kt < KTH; ++kt) {                                      \
            ahh[kt] = *reinterpret_cast<const bf16x8*>(hrd[CUR][kt]);           \
            ahl[kt] = *reinterpret_cast<const bf16x8*>(hrd[CUR][kt] + HPLANE);  \
        }                                                                       \
        f32x4 acc[4];                                                           \
        _Pragma("unroll")                                                       \
        for (int p = 0; p < 4; ++p) {                                           \
            acc[p][0] = breg[p]; acc[p][1] = breg[p];                           \
            acc[p][2] = breg[p]; acc[p][3] = breg[p];                           \
        }                                                                       \
        _Pragma("unroll")                                                       \
        for (int kt = 0; kt < KTH; ++kt)                                        \
        _Pragma("unroll")                                                       \
        for (int p = 0; p < 4; ++p) {                                           \
            acc[p] = __builtin_amdgcn_mfma_f32_16x16x32_bf16(ahh[kt], bwh[p][kt], acc[p], 0, 0, 0); \
            acc[p] = __builtin_amdgcn_mfma_f32_16x16x32_bf16(ahh[kt], bwl[p][kt], acc[p], 0, 0, 0); \
            acc[p] = __builtin_amdgcn_mfma_f32_16x16x32_bf16(ahl[kt], bwh[p][kt], acc[p], 0, 0, 0); \
        }                                                                       \
        _Pragma("unroll")                                                       \
        for (int kt = 0; kt < KTX; ++kt) {                                      \
            const bool live = (kt < KTX - 1) || (lq < KTAIL);                   \
            _Pragma("unroll")                                                   \
            for (int p = 0; p < 4; ++p) {                                       \
                bf16x8 wh = {}, wl = {};                                        \
                if (live) {                                                     \
                    wh = *reinterpret_cast<const bf16x8*>(wrh[kt] + p * U * 8); \
                    wl = *reinterpret_cast<const bf16x8*>(wrl[kt] + p * U * 8); \
                }                                                               \
                acc[p] = __builtin_amdgcn_mfma_f32_16x16x32_bf16(xph[kt], wh, acc[p], 0, 0, 0); \
                acc[p] = __builtin_amdgcn_mfma_f32_16x16x32_bf16(xph[kt], wl, acc[p], 0, 0, 0); \
                acc[p] = __builtin_amdgcn_mfma_f32_16x16x32_bf16(xpl[kt], wh, acc[p], 0, 0, 0); \
            }                                                                   \
        }                                                                       \
        if ((tcur) + 1 < T_STEPS) {                                             \
            pxh += KXD; pxl += KXD;                                             \
            _Pragma("unroll")                                                   \
            for (int kt = 0; kt < KTX; ++kt)                                    \
                if (kt < KTX - 1 || lq < KTAIL) {                               \
                    xph[kt] = *reinterpret_cast<const bf16x8*>(pxh + kt * 32);  \
                    xpl[kt] = *reinterpret_cast<const bf16x8*>(pxl + kt * 32);  \
                }                                                               \
        }                                                                       \
        _Pragma("unroll")                                                       \
        for (int r = 0; r < 4; ++r) {                                           \
            float si = fast_sigmoid(acc[0][r]);                                 \
            float sf = fast_sigmoid(acc[1][r]);                                 \
            float g  = fmaxf(acc[2][r], 0.f);                                   \
            float so = fast_sigmoid(acc[3][r]);                                 \
            float c  = sf * creg[r] + si * g;                                   \
            creg[r] = c;                                                        \
            float h = so * fmaxf(c, 0.f);                                       \
            unsigned s = split2(h);                                             \
            u16* hw = (OTH) ? hw1 : hw0;                                        \
            hw[r * 8] = (u16)(s >> 16);                                         \
            hw[HPLANE + r * 8] = (u16)s;                                        \
            if constexpr (!LAST_ONLY) {                                         \
                size_t o = ho + (size_t)r * (T_STEPS * U) + (size_t)(tcur) * U; \
                hhi[o] = (u16)(s >> 16);                                        \
                hlo[o] = (u16)s;                                                \
            } else {                                                            \
                if ((tcur) == T_STEPS - 1)                                      \
                    hlast[(size_t)(b0 + lq * 4 + r) * U + unit] = h;            \
            }                                                                   \
        }                                                                       \
        block_sync_lds();                                                       \
    }

    for (int t = 0; t < T_STEPS; t += 2) {
        STEP(0, 1, t)
        STEP(1, 0, t + 1)
    }
#undef STEP
}

// Dense head: one wave per batch row. 64 ->relu-> 64 ->relu-> 32 -> 101 -> softmax
__global__ __launch_bounds__(256)
void dense_head(const float* __restrict__ h3,    // (B,64)
                const float* __restrict__ Wd1, const float* __restrict__ bd1,
                const float* __restrict__ Wd2, const float* __restrict__ bd2,
                const float* __restrict__ Wd3, const float* __restrict__ bd3,
                float* __restrict__ out)         // (B,101)
{
    __shared__ float s1[4][64];
    __shared__ float s2[4][32];
    const int w    = threadIdx.x >> 6;
    const int lane = threadIdx.x & 63;
    const int row  = blockIdx.x * 4 + w;

    float hval = h3[(size_t)row * 64 + lane];
    float a = bd1[lane];
#pragma unroll
    for (int k = 0; k < 64; ++k) {
        float hk = __shfl(hval, k, 64);
        a = fmaf(hk, Wd1[k * 64 + lane], a);
    }
    s1[w][lane] = fmaxf(a, 0.f);
    __syncthreads();

    if (lane < 32) {
        float a2 = bd2[lane];
#pragma unroll
        for (int k = 0; k < 64; ++k) a2 = fmaf(s1[w][k], Wd2[k * 32 + lane], a2);
        s2[w][lane] = fmaxf(a2, 0.f);
    }
    __syncthreads();

    float a0 = bd3[lane];
#pragma unroll
    for (int k = 0; k < 32; ++k) a0 = fmaf(s2[w][k], Wd3[k * 101 + lane], a0);
    float a1 = -INFINITY;
    if (lane < 37) {
        a1 = bd3[64 + lane];
#pragma unroll
        for (int k = 0; k < 32; ++k) a1 = fmaf(s2[w][k], Wd3[k * 101 + 64 + lane], a1);
    }

    float m = fmaxf(a0, a1);
#pragma unroll
    for (int off = 32; off > 0; off >>= 1) m = fmaxf(m, __shfl_xor(m, off, 64));
    float e0 = expf(a0 - m);
    float e1 = (lane < 37) ? expf(a1 - m) : 0.f;
    float s = e0 + e1;
#pragma unroll
    for (int off = 32; off > 0; off >>= 1) s += __shfl_xor(s, off, 64);

    out[(size_t)row * 101 + lane] = e0 / s;
    if (lane < 37) out[(size_t)row * 101 + 64 + lane] = e1 / s;
}

extern "C" void kernel_launch(void* const* d_in, const int* in_sizes, int n_in,
                              void* d_out, int out_size, void* d_ws, size_t ws_size,
                              hipStream_t stream) {
    const float* x   = (const float*)d_in[0];
    const float* W1  = (const float*)d_in[1];
    const float* U1  = (const float*)d_in[2];
    const float* b1  = (const float*)d_in[3];
    const float* W2  = (const float*)d_in[4];
    const float* U2  = (const float*)d_in[5];
    const float* b2  = (const float*)d_in[6];
    const float* W3  = (const float*)d_in[7];
    const float* U3  = (const float*)d_in[8];
    const float* b3  = (const float*)d_in[9];
    const float* Wd1 = (const float*)d_in[10];
    const float* bd1 = (const float*)d_in[11];
    const float* Wd2 = (const float*)d_in[12];
    const float* bd2 = (const float*)d_in[13];
    const float* Wd3 = (const float*)d_in[14];
    const float* bd3 = (const float*)d_in[15];

    // workspace (u16 units). Region A (x planes) is reused for h2 planes
    // after L1 consumes x. Total footprint ~102 MB.
    u16* ws16 = (u16*)d_ws;
    u16* xhi  = ws16;                         // 1024*120*144 = 17,694,720
    u16* xlo  = xhi + 17694720;               // ends at 35,389,440
    u16* h2hi = ws16;                         // alias (x dead after L1)
    u16* h2lo = h2hi + 15728640;              // 1024*120*128; ends 31,457,280
    u16* h1hi = ws16 + 35389440;              // 1024*120*64 = 7,864,320
    u16* h1lo = h1hi + 7864320;               // ends 51,118,080
    float* h3 = (float*)(ws16 + 51118080);    // 1024*64 fp32

    // 1) split/pad input x -> planes
    xconv<<<(BATCH * T_STEPS * 144) / 256, 256, 0, stream>>>(x, xhi, xlo);
    // 2) layer 1: U=64, Kx data 144 (5 tiles, tail half-valid)
    lstm_fused<64, 144, 5, 2, 4, false><<<64, 256, 0, stream>>>(
        xhi, xlo, W1, 132, U1, b1, h1hi, h1lo, nullptr);
    // 3) layer 2: U=128, Kx = 64 (2 tiles)
    lstm_fused<128, 64, 2, 4, 8, false><<<64, 512, 0, stream>>>(
        h1hi, h1lo, W2, 64, U2, b2, h2hi, h2lo, nullptr);
    // 4) layer 3: U=64, Kx = 128 (4 tiles), last h only (fp32)
    lstm_fused<64, 128, 4, 4, 4, true><<<64, 256, 0, stream>>>(
        h2hi, h2lo, W3, 128, U3, b3, nullptr, nullptr, h3);
    // 5) dense head + softmax
    dense_head<<<BATCH / 4, 256, 0, stream>>>(h3, Wd1, bd1, Wd2, bd2, Wd3, bd3,
                                              (float*)d_out);
}

// Round 10
// 788.673 us; speedup vs baseline: 1.1155x; 1.0229x over previous
//
#include <hip/hip_runtime.h>
#include <math.h>

#define T_STEPS 120
#define BATCH   1024

typedef __attribute__((ext_vector_type(8))) short bf16x8;
typedef __attribute__((ext_vector_type(4))) float f32x4;
typedef unsigned short u16;

// split f into hi (truncated bf16) + lo (RNE bf16 of remainder); f ~= hi+lo
// returns (hi << 16) | lo
__device__ __forceinline__ unsigned split2(float f) {
    union { float f; unsigned u; } a; a.f = f;
    unsigned hi = a.u >> 16;
    union { float f; unsigned u; } h; h.u = a.u & 0xFFFF0000u;
    union { float f; unsigned u; } b; b.f = f - h.f;
    unsigned rr = b.u + 0x7FFFu + ((b.u >> 16) & 1);
    return (hi << 16) | (rr >> 16);
}

__device__ __forceinline__ float fast_sigmoid(float x) {
    float e = __expf(-x);
    return __builtin_amdgcn_rcpf(1.f + e);
}

// LDS-visibility-only barrier: does NOT drain vmcnt, so global prefetch
// loads and h stores stay in flight across the step boundary.
__device__ __forceinline__ void block_sync_lds() {
    asm volatile("s_waitcnt lgkmcnt(0)" ::: "memory");
    __builtin_amdgcn_sched_barrier(0);
    __builtin_amdgcn_s_barrier();
    __builtin_amdgcn_sched_barrier(0);
}

// ---------------------------------------------------------------------------
// x (B,T,132) fp32 -> split bf16 hi/lo planes (B,T,144), zero-padded.
// ---------------------------------------------------------------------------
__global__ __launch_bounds__(256)
void xconv(const float* __restrict__ x, u16* __restrict__ xhi, u16* __restrict__ xlo)
{
    int idx = blockIdx.x * 256 + threadIdx.x;
    int k   = idx % 144;
    int bt  = idx / 144;
    float f = (k < 132) ? x[(size_t)bt * 132 + k] : 0.f;
    unsigned s = split2(f);
    xhi[idx] = (u16)(s >> 16);
    xlo[idx] = (u16)s;
}

// ---------------------------------------------------------------------------
// Fused LSTM layer, 512 threads = 8 waves, grid = 64 (16 batch rows/block).
// SPLIT mode (L1/L3, U=64): waves 0-3 = h-waves (recurrence + gates),
//   waves 4-7 = x-waves (x@W feed-forward, one step ahead, partials via LDS).
// Combined mode (L2, U=128): 8 waves each do h-part + x-part for 16 units.
// W and U weights register-resident (pre-split bf16 hi/lo). h in LDS planes,
// double-buffered; x-partial planes stride-20-padded f32, double-buffered.
// One lgkm-only barrier per step.
// ---------------------------------------------------------------------------
template<int U, int KXD, int KTX, int KTAIL, bool SPLIT, bool LAST_ONLY>
__global__ __launch_bounds__(512, 2)
void lstm_fused(const u16* __restrict__ xhi, const u16* __restrict__ xlo,
                const float* __restrict__ W, int KIN,
                const float* __restrict__ Uw, const float* __restrict__ bias,
                u16* __restrict__ hhi, u16* __restrict__ hlo,
                float* __restrict__ hlast)
{
    constexpr int NZ  = 4 * U;
    constexpr int KTH = U / 32;
    constexpr int NB  = 16;
    constexpr int HPLANE = NB * U;              // u16 per h plane per buffer
    constexpr int NGRP = SPLIT ? (U / 16) : (U / 16);  // unit groups (4 or 8)
    constexpr int XPSTRIDE = 20;                // f32; pad -> 2-way banks, 16B aligned

    __shared__ u16 hsh[4 * HPLANE];             // [buf][hi/lo][NB*U]
    __shared__ float xp[SPLIT ? 2 * NZ * XPSTRIDE : 4];

    const int tid  = threadIdx.x;
    const int lane = tid & 63;
    const int wid  = tid >> 6;
    const int ln   = lane & 15;
    const int lq   = lane >> 4;
    const bool ish = (!SPLIT) || (wid < NGRP);
    const int g    = SPLIT ? (ish ? wid : wid - NGRP) : wid;
    const int unit = g * 16 + ln;
    const int b0   = blockIdx.x * NB;

    if (ish) {
        // =================== h-wave (or combined wave) ===================
        // U-weights into registers, pre-split
        bf16x8 bwh[4][KTH], bwl[4][KTH];
#pragma unroll
        for (int p = 0; p < 4; ++p)
#pragma unroll
            for (int kt = 0; kt < KTH; ++kt)
#pragma unroll
                for (int e = 0; e < 8; ++e) {
                    int k = kt * 32 + lq * 8 + e;
                    unsigned s = split2(Uw[(size_t)k * NZ + p * U + unit]);
                    bwh[p][kt][e] = (short)(s >> 16);
                    bwl[p][kt][e] = (short)(s & 0xFFFFu);
                }
        float breg[4];
#pragma unroll
        for (int p = 0; p < 4; ++p) breg[p] = bias[p * U + unit];

        // combined mode: W-weights + x frags too
        bf16x8 wxh[KTX][4], wxl[KTX][4];
        bf16x8 xfh[KTX], xfl[KTX];
        const u16 *pxh = nullptr, *pxl = nullptr;
        if constexpr (!SPLIT) {
#pragma unroll
            for (int kt = 0; kt < KTX; ++kt)
#pragma unroll
                for (int p = 0; p < 4; ++p)
#pragma unroll
                    for (int e = 0; e < 8; ++e) {
                        int k = kt * 32 + lq * 8 + e;
                        float f = (k < KIN) ? W[(size_t)k * NZ + p * U + unit] : 0.f;
                        unsigned s = split2(f);
                        wxh[kt][p][e] = (short)(s >> 16);
                        wxl[kt][p][e] = (short)(s & 0xFFFFu);
                    }
            pxh = xhi + ((size_t)(b0 + ln) * T_STEPS) * KXD + lq * 8;
            pxl = xlo + ((size_t)(b0 + ln) * T_STEPS) * KXD + lq * 8;
#pragma unroll
            for (int kt = 0; kt < KTX; ++kt) {
                xfh[kt] = *reinterpret_cast<const bf16x8*>(pxh + kt * 32);
                xfl[kt] = *reinterpret_cast<const bf16x8*>(pxl + kt * 32);
            }
        }

        // h state init: zero both planes of buf0; c = 0
        u16* hw0 = hsh + ((unit >> 3) * NB + lq * 4) * 8 + (unit & 7);
        u16* hw1 = hw0 + 2 * HPLANE;
        float creg[4];
#pragma unroll
        for (int r = 0; r < 4; ++r) {
            creg[r] = 0.f;
            hw0[r * 8] = 0;
            hw0[HPLANE + r * 8] = 0;
        }

        const u16* hrd[2][KTH];
#pragma unroll
        for (int b = 0; b < 2; ++b)
#pragma unroll
            for (int kt = 0; kt < KTH; ++kt)
                hrd[b][kt] = hsh + b * 2 * HPLANE + ((kt * 4 + lq) * NB + ln) * 8;

        const float* xprd[2];
        xprd[0] = xp + (size_t)0 * NZ * XPSTRIDE;
        xprd[1] = xp + (size_t)1 * NZ * XPSTRIDE;

        size_t ho = ((size_t)(b0 + lq * 4) * T_STEPS) * U + unit;

        block_sync_lds();

#define HSTEP(CUR, OTH, tc)                                                     \
    {                                                                           \
        bf16x8 ahh[KTH], ahl[KTH];                                              \
        _Pragma("unroll")                                                       \
        for (int kt = 0; kt < KTH; ++kt) {                                      \
            ahh[kt] = *reinterpret_cast<const bf16x8*>(hrd[CUR][kt]);           \
            ahl[kt] = *reinterpret_cast<const bf16x8*>(hrd[CUR][kt] + HPLANE);  \
        }                                                                       \
        f32x4 acc[4];                                                           \
        if constexpr (SPLIT) {                                                  \
            _Pragma("unroll")                                                   \
            for (int p = 0; p < 4; ++p) {                                       \
                f32x4 v = *reinterpret_cast<const f32x4*>(                      \
                    xprd[CUR] + (p * U + unit) * XPSTRIDE + lq * 4);            \
                acc[p][0] = v[0] + breg[p]; acc[p][1] = v[1] + breg[p];         \
                acc[p][2] = v[2] + breg[p]; acc[p][3] = v[3] + breg[p];         \
            }                                                                   \
        } else {                                                                \
            _Pragma("unroll")                                                   \
            for (int p = 0; p < 4; ++p) {                                       \
                acc[p][0] = breg[p]; acc[p][1] = breg[p];                       \
                acc[p][2] = breg[p]; acc[p][3] = breg[p];                       \
            }                                                                   \
        }                                                                       \
        _Pragma("unroll")                                                       \
        for (int kt = 0; kt < KTH; ++kt)                                        \
        _Pragma("unroll")                                                       \
        for (int p = 0; p < 4; ++p) {                                           \
            acc[p] = __builtin_amdgcn_mfma_f32_16x16x32_bf16(ahh[kt], bwh[p][kt], acc[p], 0, 0, 0); \
            acc[p] = __builtin_amdgcn_mfma_f32_16x16x32_bf16(ahh[kt], bwl[p][kt], acc[p], 0, 0, 0); \
            acc[p] = __builtin_amdgcn_mfma_f32_16x16x32_bf16(ahl[kt], bwh[p][kt], acc[p], 0, 0, 0); \
        }                                                                       \
        if constexpr (!SPLIT) {                                                 \
            _Pragma("unroll")                                                   \
            for (int kt = 0; kt < KTX; ++kt)                                    \
            _Pragma("unroll")                                                   \
            for (int p = 0; p < 4; ++p) {                                       \
                acc[p] = __builtin_amdgcn_mfma_f32_16x16x32_bf16(xfh[kt], wxh[kt][p], acc[p], 0, 0, 0); \
                acc[p] = __builtin_amdgcn_mfma_f32_16x16x32_bf16(xfh[kt], wxl[kt][p], acc[p], 0, 0, 0); \
                acc[p] = __builtin_amdgcn_mfma_f32_16x16x32_bf16(xfl[kt], wxh[kt][p], acc[p], 0, 0, 0); \
            }                                                                   \
            if ((tc) + 1 < T_STEPS) {                                           \
                pxh += KXD; pxl += KXD;                                         \
                _Pragma("unroll")                                               \
                for (int kt = 0; kt < KTX; ++kt) {                              \
                    xfh[kt] = *reinterpret_cast<const bf16x8*>(pxh + kt * 32);  \
                    xfl[kt] = *reinterpret_cast<const bf16x8*>(pxl + kt * 32);  \
                }                                                               \
            }                                                                   \
        }                                                                       \
        _Pragma("unroll")                                                       \
        for (int r = 0; r < 4; ++r) {                                           \
            float si = fast_sigmoid(acc[0][r]);                                 \
            float sf = fast_sigmoid(acc[1][r]);                                 \
            float gg = fmaxf(acc[2][r], 0.f);                                   \
            float so = fast_sigmoid(acc[3][r]);                                 \
            float c  = sf * creg[r] + si * gg;                                  \
            creg[r] = c;                                                        \
            float h = so * fmaxf(c, 0.f);                                       \
            unsigned s = split2(h);                                             \
            u16* hw = (OTH) ? hw1 : hw0;                                        \
            hw[r * 8] = (u16)(s >> 16);                                         \
            hw[HPLANE + r * 8] = (u16)s;                                        \
            if constexpr (!LAST_ONLY) {                                         \
                size_t o = ho + (size_t)r * (T_STEPS * U) + (size_t)(tc) * U;   \
                hhi[o] = (u16)(s >> 16);                                        \
                hlo[o] = (u16)s;                                                \
            } else {                                                            \
                if ((tc) == T_STEPS - 1)                                        \
                    hlast[(size_t)(b0 + lq * 4 + r) * U + unit] = h;            \
            }                                                                   \
        }                                                                       \
        block_sync_lds();                                                       \
    }

        for (int t = 0; t < T_STEPS; t += 2) {
            HSTEP(0, 1, t)
            HSTEP(1, 0, t + 1)
        }
#undef HSTEP
    } else {
        // =================== x-wave (SPLIT mode only) ===================
        // W-weights into registers, pre-split (zero for k >= KIN)
        bf16x8 wxh[KTX][4], wxl[KTX][4];
#pragma unroll
        for (int kt = 0; kt < KTX; ++kt)
#pragma unroll
            for (int p = 0; p < 4; ++p)
#pragma unroll
                for (int e = 0; e < 8; ++e) {
                    int k = kt * 32 + lq * 8 + e;
                    float f = (k < KIN) ? W[(size_t)k * NZ + p * U + unit] : 0.f;
                    unsigned s = split2(f);
                    wxh[kt][p][e] = (short)(s >> 16);
                    wxl[kt][p][e] = (short)(s & 0xFFFFu);
                }

        const u16* pxh = xhi + ((size_t)(b0 + ln) * T_STEPS) * KXD + lq * 8;
        const u16* pxl = xlo + ((size_t)(b0 + ln) * T_STEPS) * KXD + lq * 8;

        float* xpw[2];
        xpw[0] = xp + (size_t)0 * NZ * XPSTRIDE + (size_t)0;
        xpw[1] = xp + (size_t)1 * NZ * XPSTRIDE + (size_t)0;

        // frags for step 0
        bf16x8 xfh[KTX] = {}, xfl[KTX] = {};
#pragma unroll
        for (int kt = 0; kt < KTX; ++kt)
            if (kt < KTX - 1 || lq < KTAIL) {
                xfh[kt] = *reinterpret_cast<const bf16x8*>(pxh + kt * 32);
                xfl[kt] = *reinterpret_cast<const bf16x8*>(pxl + kt * 32);
            }

        // partial for t=0 into buf0
        {
            f32x4 xacc[4] = {};
#pragma unroll
            for (int kt = 0; kt < KTX; ++kt)
#pragma unroll
                for (int p = 0; p < 4; ++p) {
                    xacc[p] = __builtin_amdgcn_mfma_f32_16x16x32_bf16(xfh[kt], wxh[kt][p], xacc[p], 0, 0, 0);
                    xacc[p] = __builtin_amdgcn_mfma_f32_16x16x32_bf16(xfh[kt], wxl[kt][p], xacc[p], 0, 0, 0);
                    xacc[p] = __builtin_amdgcn_mfma_f32_16x16x32_bf16(xfl[kt], wxh[kt][p], xacc[p], 0, 0, 0);
                }
#pragma unroll
            for (int p = 0; p < 4; ++p)
                *reinterpret_cast<f32x4*>(xpw[0] + (p * U + unit) * XPSTRIDE + lq * 4) = xacc[p];
            // frags for step 1
            pxh += KXD; pxl += KXD;
#pragma unroll
            for (int kt = 0; kt < KTX; ++kt)
                if (kt < KTX - 1 || lq < KTAIL) {
                    xfh[kt] = *reinterpret_cast<const bf16x8*>(pxh + kt * 32);
                    xfl[kt] = *reinterpret_cast<const bf16x8*>(pxl + kt * 32);
                }
        }

        block_sync_lds();

#define XSTEP(OTH, tc)                                                          \
    {                                                                           \
        if ((tc) + 1 < T_STEPS) {                                               \
            f32x4 xacc[4] = {};                                                 \
            _Pragma("unroll")                                                   \
            for (int kt = 0; kt < KTX; ++kt)                                    \
            _Pragma("unroll")                                                   \
            for (int p = 0; p < 4; ++p) {                                       \
                xacc[p] = __builtin_amdgcn_mfma_f32_16x16x32_bf16(xfh[kt], wxh[kt][p], xacc[p], 0, 0, 0); \
                xacc[p] = __builtin_amdgcn_mfma_f32_16x16x32_bf16(xfh[kt], wxl[kt][p], xacc[p], 0, 0, 0); \
                xacc[p] = __builtin_amdgcn_mfma_f32_16x16x32_bf16(xfl[kt], wxh[kt][p], xacc[p], 0, 0, 0); \
            }                                                                   \
            _Pragma("unroll")                                                   \
            for (int p = 0; p < 4; ++p)                                         \
                *reinterpret_cast<f32x4*>(xpw[OTH] + (p * U + unit) * XPSTRIDE + lq * 4) = xacc[p]; \
            if ((tc) + 2 < T_STEPS) {                                           \
                pxh += KXD; pxl += KXD;                                         \
                _Pragma("unroll")                                               \
                for (int kt = 0; kt < KTX; ++kt)                                \
                    if (kt < KTX - 1 || lq < KTAIL) {                           \
                        xfh[kt] = *reinterpret_cast<const bf16x8*>(pxh + kt * 32); \
                        xfl[kt] = *reinterpret_cast<const bf16x8*>(pxl + kt * 32); \
                    }                                                           \
            }                                                                   \
        }                                                                       \
        block_sync_lds();                                                       \
    }

        for (int t = 0; t < T_STEPS; t += 2) {
            XSTEP(1, t)
            XSTEP(0, t + 1)
        }
#undef XSTEP
    }
}

// Dense head: one wave per batch row. 64 ->relu-> 64 ->relu-> 32 -> 101 -> softmax
__global__ __launch_bounds__(256)
void dense_head(const float* __restrict__ h3,    // (B,64)
                const float* __restrict__ Wd1, const float* __restrict__ bd1,
                const float* __restrict__ Wd2, const float* __restrict__ bd2,
                const float* __restrict__ Wd3, const float* __restrict__ bd3,
                float* __restrict__ out)         // (B,101)
{
    __shared__ float s1[4][64];
    __shared__ float s2[4][32];
    const int w    = threadIdx.x >> 6;
    const int lane = threadIdx.x & 63;
    const int row  = blockIdx.x * 4 + w;

    float hval = h3[(size_t)row * 64 + lane];
    float a = bd1[lane];
#pragma unroll
    for (int k = 0; k < 64; ++k) {
        float hk = __shfl(hval, k, 64);
        a = fmaf(hk, Wd1[k * 64 + lane], a);
    }
    s1[w][lane] = fmaxf(a, 0.f);
    __syncthreads();

    if (lane < 32) {
        float a2 = bd2[lane];
#pragma unroll
        for (int k = 0; k < 64; ++k) a2 = fmaf(s1[w][k], Wd2[k * 32 + lane], a2);
        s2[w][lane] = fmaxf(a2, 0.f);
    }
    __syncthreads();

    float a0 = bd3[lane];
#pragma unroll
    for (int k = 0; k < 32; ++k) a0 = fmaf(s2[w][k], Wd3[k * 101 + lane], a0);
    float a1 = -INFINITY;
    if (lane < 37) {
        a1 = bd3[64 + lane];
#pragma unroll
        for (int k = 0; k < 32; ++k) a1 = fmaf(s2[w][k], Wd3[k * 101 + 64 + lane], a1);
    }

    float m = fmaxf(a0, a1);
#pragma unroll
    for (int off = 32; off > 0; off >>= 1) m = fmaxf(m, __shfl_xor(m, off, 64));
    float e0 = expf(a0 - m);
    float e1 = (lane < 37) ? expf(a1 - m) : 0.f;
    float s = e0 + e1;
#pragma unroll
    for (int off = 32; off > 0; off >>= 1) s += __shfl_xor(s, off, 64);

    out[(size_t)row * 101 + lane] = e0 / s;
    if (lane < 37) out[(size_t)row * 101 + 64 + lane] = e1 / s;
}

extern "C" void kernel_launch(void* const* d_in, const int* in_sizes, int n_in,
                              void* d_out, int out_size, void* d_ws, size_t ws_size,
                              hipStream_t stream) {
    const float* x   = (const float*)d_in[0];
    const float* W1  = (const float*)d_in[1];
    const float* U1  = (const float*)d_in[2];
    const float* b1  = (const float*)d_in[3];
    const float* W2  = (const float*)d_in[4];
    const float* U2  = (const float*)d_in[5];
    const float* b2  = (const float*)d_in[6];
    const float* W3  = (const float*)d_in[7];
    const float* U3  = (const float*)d_in[8];
    const float* b3  = (const float*)d_in[9];
    const float* Wd1 = (const float*)d_in[10];
    const float* bd1 = (const float*)d_in[11];
    const float* Wd2 = (const float*)d_in[12];
    const float* bd2 = (const float*)d_in[13];
    const float* Wd3 = (const float*)d_in[14];
    const float* bd3 = (const float*)d_in[15];

    // workspace (u16 units). x planes aliased by h2 planes after L1.
    u16* ws16 = (u16*)d_ws;
    u16* xhi  = ws16;                         // 1024*120*144 = 17,694,720
    u16* xlo  = xhi + 17694720;               // ends at 35,389,440
    u16* h2hi = ws16;                         // alias (x dead after L1)
    u16* h2lo = h2hi + 15728640;              // 1024*120*128; ends 31,457,280
    u16* h1hi = ws16 + 35389440;              // 1024*120*64 = 7,864,320
    u16* h1lo = h1hi + 7864320;               // ends 51,118,080
    float* h3 = (float*)(ws16 + 51118080);    // 1024*64 fp32

    // 1) split/pad input x -> planes
    xconv<<<(BATCH * T_STEPS * 144) / 256, 256, 0, stream>>>(x, xhi, xlo);
    // 2) layer 1: U=64, Kx 144 (5 tiles, tail half), SPLIT x/h waves
    lstm_fused<64, 144, 5, 2, true, false><<<64, 512, 0, stream>>>(
        xhi, xlo, W1, 132, U1, b1, h1hi, h1lo, nullptr);
    // 3) layer 2: U=128, Kx 64 (2 tiles), combined waves
    lstm_fused<128, 64, 2, 4, false, false><<<64, 512, 0, stream>>>(
        h1hi, h1lo, W2, 64, U2, b2, h2hi, h2lo, nullptr);
    // 4) layer 3: U=64, Kx 128 (4 tiles), SPLIT, last h only (fp32)
    lstm_fused<64, 128, 4, 4, true, true><<<64, 512, 0, stream>>>(
        h2hi, h2lo, W3, 128, U3, b3, nullptr, nullptr, h3);
    // 5) dense head + softmax
    dense_head<<<BATCH / 4, 256, 0, stream>>>(h3, Wd1, bd1, Wd2, bd2, Wd3, bd3,
                                              (float*)d_out);
}

// Round 11
// 562.595 us; speedup vs baseline: 1.5638x; 1.4018x over previous
//
#include <hip/hip_runtime.h>
#include <math.h>

#define T_STEPS 120
#define BATCH   1024

typedef __attribute__((ext_vector_type(8))) short bf16x8;
typedef __attribute__((ext_vector_type(4))) float f32x4;
typedef unsigned short u16;

// split f into hi (truncated bf16) + lo (RNE bf16 of remainder); f ~= hi+lo
// returns (hi << 16) | lo
__device__ __forceinline__ unsigned split2(float f) {
    union { float f; unsigned u; } a; a.f = f;
    unsigned hi = a.u >> 16;
    union { float f; unsigned u; } h; h.u = a.u & 0xFFFF0000u;
    union { float f; unsigned u; } b; b.f = f - h.f;
    unsigned rr = b.u + 0x7FFFu + ((b.u >> 16) & 1);
    return (hi << 16) | (rr >> 16);
}

// round-to-nearest-even bf16 (for static weights; ~2^-9 relative, passes
// through the contractive recurrence at ~1e-5 final output error)
__device__ __forceinline__ short bf16rne(float f) {
    union { float f; unsigned u; } a; a.f = f;
    unsigned r = a.u + 0x7FFFu + ((a.u >> 16) & 1);
    return (short)(r >> 16);
}

__device__ __forceinline__ float fast_sigmoid(float x) {
    float e = __expf(-x);
    return __builtin_amdgcn_rcpf(1.f + e);
}

// LDS-visibility-only barrier: does NOT drain vmcnt, so global prefetch
// loads and h stores stay in flight across the step boundary.
__device__ __forceinline__ void block_sync_lds() {
    asm volatile("s_waitcnt lgkmcnt(0)" ::: "memory");
    __builtin_amdgcn_sched_barrier(0);
    __builtin_amdgcn_s_barrier();
    __builtin_amdgcn_sched_barrier(0);
}

// ---------------------------------------------------------------------------
// x (B,T,132) fp32 -> split bf16 hi/lo planes (B,T,144), zero-padded.
// ---------------------------------------------------------------------------
__global__ __launch_bounds__(256)
void xconv(const float* __restrict__ x, u16* __restrict__ xhi, u16* __restrict__ xlo)
{
    int idx = blockIdx.x * 256 + threadIdx.x;
    int k   = idx % 144;
    int bt  = idx / 144;
    float f = (k < 132) ? x[(size_t)bt * 132 + k] : 0.f;
    unsigned s = split2(f);
    xhi[idx] = (u16)(s >> 16);
    xlo[idx] = (u16)s;
}

// ---------------------------------------------------------------------------
// Fused LSTM layer, 512 threads = 8 waves, grid = 64 (16 batch rows/block).
// SPLIT mode (L1/L3, U=64): waves 0-3 = h-waves (recurrence + gates),
//   waves 4-7 = x-waves (x@W feed-forward, one step ahead, partials via LDS).
// Combined mode (L2, U=128): 8 waves each do h-part + x-part for 16 units.
// Weights: single RNE-bf16, register-resident. Activations: hi/lo split
// (2-term MFMA per weight). __launch_bounds__(512,1): 1 block/CU -> 256-VGPR
// budget, 2 waves/SIMD by construction. h in LDS planes, double-buffered;
// x-partial planes stride-20-padded f32, double-buffered. One lgkm-only
// barrier per step.
// ---------------------------------------------------------------------------
template<int U, int KXD, int KTX, int KTAIL, bool SPLIT, bool LAST_ONLY>
__global__ __launch_bounds__(512, 1)
void lstm_fused(const u16* __restrict__ xhi, const u16* __restrict__ xlo,
                const float* __restrict__ W, int KIN,
                const float* __restrict__ Uw, const float* __restrict__ bias,
                u16* __restrict__ hhi, u16* __restrict__ hlo,
                float* __restrict__ hlast)
{
    constexpr int NZ  = 4 * U;
    constexpr int KTH = U / 32;
    constexpr int NB  = 16;
    constexpr int HPLANE = NB * U;              // u16 per h plane per buffer
    constexpr int NGRP = U / 16;                // unit groups (4 or 8)
    constexpr int XPSTRIDE = 20;                // f32; pad -> 2-way banks, 16B aligned

    __shared__ u16 hsh[4 * HPLANE];             // [buf][hi/lo][NB*U]
    __shared__ float xp[SPLIT ? 2 * NZ * XPSTRIDE : 4];

    const int tid  = threadIdx.x;
    const int lane = tid & 63;
    const int wid  = tid >> 6;
    const int ln   = lane & 15;
    const int lq   = lane >> 4;
    const bool ish = (!SPLIT) || (wid < NGRP);
    const int g    = SPLIT ? (ish ? wid : wid - NGRP) : wid;
    const int unit = g * 16 + ln;
    const int b0   = blockIdx.x * NB;

    if (ish) {
        // =================== h-wave (or combined wave) ===================
        // U-weights into registers, single bf16
        bf16x8 bwu[4][KTH];
#pragma unroll
        for (int p = 0; p < 4; ++p)
#pragma unroll
            for (int kt = 0; kt < KTH; ++kt)
#pragma unroll
                for (int e = 0; e < 8; ++e) {
                    int k = kt * 32 + lq * 8 + e;
                    bwu[p][kt][e] = bf16rne(Uw[(size_t)k * NZ + p * U + unit]);
                }
        float breg[4];
#pragma unroll
        for (int p = 0; p < 4; ++p) breg[p] = bias[p * U + unit];

        // combined mode: W-weights + x frags too
        bf16x8 wxw[KTX][4];
        bf16x8 xfh[KTX], xfl[KTX];
        const u16 *pxh = nullptr, *pxl = nullptr;
        if constexpr (!SPLIT) {
#pragma unroll
            for (int kt = 0; kt < KTX; ++kt)
#pragma unroll
                for (int p = 0; p < 4; ++p)
#pragma unroll
                    for (int e = 0; e < 8; ++e) {
                        int k = kt * 32 + lq * 8 + e;
                        wxw[kt][p][e] = (k < KIN) ? bf16rne(W[(size_t)k * NZ + p * U + unit])
                                                  : (short)0;
                    }
            pxh = xhi + ((size_t)(b0 + ln) * T_STEPS) * KXD + lq * 8;
            pxl = xlo + ((size_t)(b0 + ln) * T_STEPS) * KXD + lq * 8;
#pragma unroll
            for (int kt = 0; kt < KTX; ++kt) {
                xfh[kt] = *reinterpret_cast<const bf16x8*>(pxh + kt * 32);
                xfl[kt] = *reinterpret_cast<const bf16x8*>(pxl + kt * 32);
            }
        }

        // h state init: zero both planes of buf0; c = 0
        u16* hw0 = hsh + ((unit >> 3) * NB + lq * 4) * 8 + (unit & 7);
        u16* hw1 = hw0 + 2 * HPLANE;
        float creg[4];
#pragma unroll
        for (int r = 0; r < 4; ++r) {
            creg[r] = 0.f;
            hw0[r * 8] = 0;
            hw0[HPLANE + r * 8] = 0;
        }

        const u16* hrd[2][KTH];
#pragma unroll
        for (int b = 0; b < 2; ++b)
#pragma unroll
            for (int kt = 0; kt < KTH; ++kt)
                hrd[b][kt] = hsh + b * 2 * HPLANE + ((kt * 4 + lq) * NB + ln) * 8;

        const float* xprd[2];
        xprd[0] = xp + (size_t)0 * NZ * XPSTRIDE;
        xprd[1] = xp + (size_t)1 * NZ * XPSTRIDE;

        size_t ho = ((size_t)(b0 + lq * 4) * T_STEPS) * U + unit;

        block_sync_lds();

#define HSTEP(CUR, OTH, tc)                                                     \
    {                                                                           \
        bf16x8 ahh[KTH], ahl[KTH];                                              \
        _Pragma("unroll")                                                       \
        for (int kt = 0; kt < KTH; ++kt) {                                      \
            ahh[kt] = *reinterpret_cast<const bf16x8*>(hrd[CUR][kt]);           \
            ahl[kt] = *reinterpret_cast<const bf16x8*>(hrd[CUR][kt] + HPLANE);  \
        }                                                                       \
        f32x4 acc[4];                                                           \
        if constexpr (SPLIT) {                                                  \
            _Pragma("unroll")                                                   \
            for (int p = 0; p < 4; ++p) {                                       \
                f32x4 v = *reinterpret_cast<const f32x4*>(                      \
                    xprd[CUR] + (p * U + unit) * XPSTRIDE + lq * 4);            \
                acc[p][0] = v[0] + breg[p]; acc[p][1] = v[1] + breg[p];         \
                acc[p][2] = v[2] + breg[p]; acc[p][3] = v[3] + breg[p];         \
            }                                                                   \
        } else {                                                                \
            _Pragma("unroll")                                                   \
            for (int p = 0; p < 4; ++p) {                                       \
                acc[p][0] = breg[p]; acc[p][1] = breg[p];                       \
                acc[p][2] = breg[p]; acc[p][3] = breg[p];                       \
            }                                                                   \
        }                                                                       \
        _Pragma("unroll")                                                       \
        for (int kt = 0; kt < KTH; ++kt)                                        \
        _Pragma("unroll")                                                       \
        for (int p = 0; p < 4; ++p) {                                           \
            acc[p] = __builtin_amdgcn_mfma_f32_16x16x32_bf16(ahh[kt], bwu[p][kt], acc[p], 0, 0, 0); \
            acc[p] = __builtin_amdgcn_mfma_f32_16x16x32_bf16(ahl[kt], bwu[p][kt], acc[p], 0, 0, 0); \
        }                                                                       \
        if constexpr (!SPLIT) {                                                 \
            _Pragma("unroll")                                                   \
            for (int kt = 0; kt < KTX; ++kt)                                    \
            _Pragma("unroll")                                                   \
            for (int p = 0; p < 4; ++p) {                                       \
                acc[p] = __builtin_amdgcn_mfma_f32_16x16x32_bf16(xfh[kt], wxw[kt][p], acc[p], 0, 0, 0); \
                acc[p] = __builtin_amdgcn_mfma_f32_16x16x32_bf16(xfl[kt], wxw[kt][p], acc[p], 0, 0, 0); \
            }                                                                   \
            if ((tc) + 1 < T_STEPS) {                                           \
                pxh += KXD; pxl += KXD;                                         \
                _Pragma("unroll")                                               \
                for (int kt = 0; kt < KTX; ++kt) {                              \
                    xfh[kt] = *reinterpret_cast<const bf16x8*>(pxh + kt * 32);  \
                    xfl[kt] = *reinterpret_cast<const bf16x8*>(pxl + kt * 32);  \
                }                                                               \
            }                                                                   \
        }                                                                       \
        _Pragma("unroll")                                                       \
        for (int r = 0; r < 4; ++r) {                                           \
            float si = fast_sigmoid(acc[0][r]);                                 \
            float sf = fast_sigmoid(acc[1][r]);                                 \
            float gg = fmaxf(acc[2][r], 0.f);                                   \
            float so = fast_sigmoid(acc[3][r]);                                 \
            float c  = sf * creg[r] + si * gg;                                  \
            creg[r] = c;                                                        \
            float h = so * fmaxf(c, 0.f);                                       \
            unsigned s = split2(h);                                             \
            u16* hw = (OTH) ? hw1 : hw0;                                        \
            hw[r * 8] = (u16)(s >> 16);                                         \
            hw[HPLANE + r * 8] = (u16)s;                                        \
            if constexpr (!LAST_ONLY) {                                         \
                size_t o = ho + (size_t)r * (T_STEPS * U) + (size_t)(tc) * U;   \
                hhi[o] = (u16)(s >> 16);                                        \
                hlo[o] = (u16)s;                                                \
            } else {                                                            \
                if ((tc) == T_STEPS - 1)                                        \
                    hlast[(size_t)(b0 + lq * 4 + r) * U + unit] = h;            \
            }                                                                   \
        }                                                                       \
        block_sync_lds();                                                       \
    }

        for (int t = 0; t < T_STEPS; t += 2) {
            HSTEP(0, 1, t)
            HSTEP(1, 0, t + 1)
        }
#undef HSTEP
    } else {
        // =================== x-wave (SPLIT mode only) ===================
        // W-weights into registers, single bf16 (zero for k >= KIN)
        bf16x8 wxw[KTX][4];
#pragma unroll
        for (int kt = 0; kt < KTX; ++kt)
#pragma unroll
            for (int p = 0; p < 4; ++p)
#pragma unroll
                for (int e = 0; e < 8; ++e) {
                    int k = kt * 32 + lq * 8 + e;
                    wxw[kt][p][e] = (k < KIN) ? bf16rne(W[(size_t)k * NZ + p * U + unit])
                                              : (short)0;
                }

        const u16* pxh = xhi + ((size_t)(b0 + ln) * T_STEPS) * KXD + lq * 8;
        const u16* pxl = xlo + ((size_t)(b0 + ln) * T_STEPS) * KXD + lq * 8;

        float* xpw[2];
        xpw[0] = xp + (size_t)0 * NZ * XPSTRIDE;
        xpw[1] = xp + (size_t)1 * NZ * XPSTRIDE;

        // frags for step 0
        bf16x8 xfh[KTX] = {}, xfl[KTX] = {};
#pragma unroll
        for (int kt = 0; kt < KTX; ++kt)
            if (kt < KTX - 1 || lq < KTAIL) {
                xfh[kt] = *reinterpret_cast<const bf16x8*>(pxh + kt * 32);
                xfl[kt] = *reinterpret_cast<const bf16x8*>(pxl + kt * 32);
            }

        // partial for t=0 into buf0
        {
            f32x4 xacc[4] = {};
#pragma unroll
            for (int kt = 0; kt < KTX; ++kt)
#pragma unroll
                for (int p = 0; p < 4; ++p) {
                    xacc[p] = __builtin_amdgcn_mfma_f32_16x16x32_bf16(xfh[kt], wxw[kt][p], xacc[p], 0, 0, 0);
                    xacc[p] = __builtin_amdgcn_mfma_f32_16x16x32_bf16(xfl[kt], wxw[kt][p], xacc[p], 0, 0, 0);
                }
#pragma unroll
            for (int p = 0; p < 4; ++p)
                *reinterpret_cast<f32x4*>(xpw[0] + (p * U + unit) * XPSTRIDE + lq * 4) = xacc[p];
            // frags for step 1
            pxh += KXD; pxl += KXD;
#pragma unroll
            for (int kt = 0; kt < KTX; ++kt)
                if (kt < KTX - 1 || lq < KTAIL) {
                    xfh[kt] = *reinterpret_cast<const bf16x8*>(pxh + kt * 32);
                    xfl[kt] = *reinterpret_cast<const bf16x8*>(pxl + kt * 32);
                }
        }

        block_sync_lds();

#define XSTEP(OTH, tc)                                                          \
    {                                                                           \
        if ((tc) + 1 < T_STEPS) {                                               \
            f32x4 xacc[4] = {};                                                 \
            _Pragma("unroll")                                                   \
            for (int kt = 0; kt < KTX; ++kt)                                    \
            _Pragma("unroll")                                                   \
            for (int p = 0; p < 4; ++p) {                                       \
                xacc[p] = __builtin_amdgcn_mfma_f32_16x16x32_bf16(xfh[kt], wxw[kt][p], xacc[p], 0, 0, 0); \
                xacc[p] = __builtin_amdgcn_mfma_f32_16x16x32_bf16(xfl[kt], wxw[kt][p], xacc[p], 0, 0, 0); \
            }                                                                   \
            _Pragma("unroll")                                                   \
            for (int p = 0; p < 4; ++p)                                         \
                *reinterpret_cast<f32x4*>(xpw[OTH] + (p * U + unit) * XPSTRIDE + lq * 4) = xacc[p]; \
            if ((tc) + 2 < T_STEPS) {                                           \
                pxh += KXD; pxl += KXD;                                         \
                _Pragma("unroll")                                               \
                for (int kt = 0; kt < KTX; ++kt)                                \
                    if (kt < KTX - 1 || lq < KTAIL) {                           \
                        xfh[kt] = *reinterpret_cast<const bf16x8*>(pxh + kt * 32); \
                        xfl[kt] = *reinterpret_cast<const bf16x8*>(pxl + kt * 32); \
                    }                                                           \
            }                                                                   \
        }                                                                       \
        block_sync_lds();                                                       \
    }

        for (int t = 0; t < T_STEPS; t += 2) {
            XSTEP(1, t)
            XSTEP(0, t + 1)
        }
#undef XSTEP
    }
}

// Dense head: one wave per batch row. 64 ->relu-> 64 ->relu-> 32 -> 101 -> softmax
__global__ __launch_bounds__(256)
void dense_head(const float* __restrict__ h3,    // (B,64)
                const float* __restrict__ Wd1, const float* __restrict__ bd1,
                const float* __restrict__ Wd2, const float* __restrict__ bd2,
                const float* __restrict__ Wd3, const float* __restrict__ bd3,
                float* __restrict__ out)         // (B,101)
{
    __shared__ float s1[4][64];
    __shared__ float s2[4][32];
    const int w    = threadIdx.x >> 6;
    const int lane = threadIdx.x & 63;
    const int row  = blockIdx.x * 4 + w;

    float hval = h3[(size_t)row * 64 + lane];
    float a = bd1[lane];
#pragma unroll
    for (int k = 0; k < 64; ++k) {
        float hk = __shfl(hval, k, 64);
        a = fmaf(hk, Wd1[k * 64 + lane], a);
    }
    s1[w][lane] = fmaxf(a, 0.f);
    __syncthreads();

    if (lane < 32) {
        float a2 = bd2[lane];
#pragma unroll
        for (int k = 0; k < 64; ++k) a2 = fmaf(s1[w][k], Wd2[k * 32 + lane], a2);
        s2[w][lane] = fmaxf(a2, 0.f);
    }
    __syncthreads();

    float a0 = bd3[lane];
#pragma unroll
    for (int k = 0; k < 32; ++k) a0 = fmaf(s2[w][k], Wd3[k * 101 + lane], a0);
    float a1 = -INFINITY;
    if (lane < 37) {
        a1 = bd3[64 + lane];
#pragma unroll
        for (int k = 0; k < 32; ++k) a1 = fmaf(s2[w][k], Wd3[k * 101 + 64 + lane], a1);
    }

    float m = fmaxf(a0, a1);
#pragma unroll
    for (int off = 32; off > 0; off >>= 1) m = fmaxf(m, __shfl_xor(m, off, 64));
    float e0 = expf(a0 - m);
    float e1 = (lane < 37) ? expf(a1 - m) : 0.f;
    float s = e0 + e1;
#pragma unroll
    for (int off = 32; off > 0; off >>= 1) s += __shfl_xor(s, off, 64);

    out[(size_t)row * 101 + lane] = e0 / s;
    if (lane < 37) out[(size_t)row * 101 + 64 + lane] = e1 / s;
}

extern "C" void kernel_launch(void* const* d_in, const int* in_sizes, int n_in,
                              void* d_out, int out_size, void* d_ws, size_t ws_size,
                              hipStream_t stream) {
    const float* x   = (const float*)d_in[0];
    const float* W1  = (const float*)d_in[1];
    const float* U1  = (const float*)d_in[2];
    const float* b1  = (const float*)d_in[3];
    const float* W2  = (const float*)d_in[4];
    const float* U2  = (const float*)d_in[5];
    const float* b2  = (const float*)d_in[6];
    const float* W3  = (const float*)d_in[7];
    const float* U3  = (const float*)d_in[8];
    const float* b3  = (const float*)d_in[9];
    const float* Wd1 = (const float*)d_in[10];
    const float* bd1 = (const float*)d_in[11];
    const float* Wd2 = (const float*)d_in[12];
    const float* bd2 = (const float*)d_in[13];
    const float* Wd3 = (const float*)d_in[14];
    const float* bd3 = (const float*)d_in[15];

    // workspace (u16 units). x planes aliased by h2 planes after L1.
    u16* ws16 = (u16*)d_ws;
    u16* xhi  = ws16;                         // 1024*120*144 = 17,694,720
    u16* xlo  = xhi + 17694720;               // ends at 35,389,440
    u16* h2hi = ws16;                         // alias (x dead after L1)
    u16* h2lo = h2hi + 15728640;              // 1024*120*128; ends 31,457,280
    u16* h1hi = ws16 + 35389440;              // 1024*120*64 = 7,864,320
    u16* h1lo = h1hi + 7864320;               // ends 51,118,080
    float* h3 = (float*)(ws16 + 51118080);    // 1024*64 fp32

    // 1) split/pad input x -> planes
    xconv<<<(BATCH * T_STEPS * 144) / 256, 256, 0, stream>>>(x, xhi, xlo);
    // 2) layer 1: U=64, Kx 144 (5 tiles, tail half), SPLIT x/h waves
    lstm_fused<64, 144, 5, 2, true, false><<<64, 512, 0, stream>>>(
        xhi, xlo, W1, 132, U1, b1, h1hi, h1lo, nullptr);
    // 3) layer 2: U=128, Kx 64 (2 tiles), combined waves
    lstm_fused<128, 64, 2, 4, false, false><<<64, 512, 0, stream>>>(
        h1hi, h1lo, W2, 64, U2, b2, h2hi, h2lo, nullptr);
    // 4) layer 3: U=64, Kx 128 (4 tiles), SPLIT, last h only (fp32)
    lstm_fused<64, 128, 4, 4, true, true><<<64, 512, 0, stream>>>(
        h2hi, h2lo, W3, 128, U3, b3, nullptr, nullptr, h3);
    // 5) dense head + softmax
    dense_head<<<BATCH / 4, 256, 0, stream>>>(h3, Wd1, bd1, Wd2, bd2, Wd3, bd3,
                                              (float*)d_out);
}